// Round 2
// baseline (185.039 us; speedup 1.0000x reference)
//
#include <hip/hip_runtime.h>

typedef _Float16 f16;
typedef f16 f16x8 __attribute__((ext_vector_type(8)));
typedef f16 f16x4 __attribute__((ext_vector_type(4)));
typedef f16 f16x2 __attribute__((ext_vector_type(2)));
typedef float f32x4 __attribute__((ext_vector_type(4)));
typedef unsigned int u32;

#define MFMA16(a, b, c) __builtin_amdgcn_mfma_f32_16x16x32_f16(a, b, c, 0, 0, 0)

#define BATCH 4
#define NHEADS 8
#define HDIM 64
#define SEQ 2048
#define DIN 512
#define DOUT 512
#define LOG2E 1.44269504f
#define C1 0.18033688f  // 0.125 * log2(e), folded into Q at qkv epilogue

__device__ __forceinline__ void gl_lds16(const void* g, const void* l) {
  __builtin_amdgcn_global_load_lds(
      (const __attribute__((address_space(1))) u32*)g,
      (__attribute__((address_space(3))) u32*)l, 16, 0, 0);
}

__device__ __forceinline__ float fexp2(float x) {
  float r;
  asm("v_exp_f32 %0, %1" : "=v"(r) : "v"(x));
  return r;
}

__device__ __forceinline__ f16x2 pk2(float a, float b) {
  return __builtin_bit_cast(f16x2, __builtin_amdgcn_cvt_pkrtz(a, b));
}

__device__ __forceinline__ f16x4 pk4(float a, float b, float c, float d) {
  f16x2 u0 = pk2(a, b), u1 = pk2(c, d);
  f16x4 r;
  r[0] = u0[0]; r[1] = u0[1]; r[2] = u1[0]; r[3] = u1[1];
  return r;
}

// ---------------------------------------------------------------------------
// prep_w: transpose+cvt weights w[k][n] fp32 -> wT[n][k] f16.  (unchanged)
// ---------------------------------------------------------------------------
__global__ __launch_bounds__(256) void prep_w(
    const float* __restrict__ wq, const float* __restrict__ wk,
    const float* __restrict__ wv, f16* __restrict__ wT) {
  __shared__ float tile[64][65];
  const float* w = blockIdx.z == 0 ? wq : (blockIdx.z == 1 ? wk : wv);
  f16* out = wT + (size_t)blockIdx.z * DIN * DOUT;
  int k0 = blockIdx.x * 64, n0 = blockIdx.y * 64;
  int t = threadIdx.x;
  int c = t & 63, rb = t >> 6;
#pragma unroll
  for (int ph = 0; ph < 16; ++ph) {
    int r = ph * 4 + rb;
    tile[r][c] = w[(size_t)(k0 + r) * DOUT + n0 + c];
  }
  __syncthreads();
#pragma unroll
  for (int ph = 0; ph < 16; ++ph) {
    int n = ph * 4 + rb;
    out[(size_t)(n0 + n) * DIN + k0 + c] = (f16)tile[c][n];
  }
}

// ---------------------------------------------------------------------------
// qkv_gemm: unchanged (verified; R7 showed reg-prefetch spills here).
// ---------------------------------------------------------------------------
__global__ __launch_bounds__(256, 3) void qkv_gemm(
    const float* __restrict__ xq, const float* __restrict__ xk,
    const float* __restrict__ xv, const f16* __restrict__ wT,
    f16* __restrict__ Qo, f16* __restrict__ Ko, f16* __restrict__ Vt) {
  __shared__ __attribute__((aligned(16))) f16 smem[16384];  // 32 KB
  f16* As = smem;          // 128x64
  f16* Bs = smem + 8192;   // 128x64
  f16* CT = smem;          // epilogue: 128x128 (aliases As+Bs)

  int gemm = blockIdx.z;
  const float* x = gemm == 0 ? xq : (gemm == 1 ? xk : xv);
  const f16* wt = wT + (size_t)gemm * DIN * DOUT;
  int bx = blockIdx.x;
  int m0 = (bx & 63) * 128, n0 = (bx >> 6) * 128;
  int t = threadIdx.x, w = t >> 6, lane = t & 63;
  int lr = lane & 15, lq = lane >> 4;
  int wm = (w >> 1) * 64, wn = (w & 1) * 64;

  // A staging (fp32 -> f16 through regs): 16 threads/row, 8 row-phases.
  int tr = t >> 4, tc = t & 15;
  const float* xg = x + (size_t)(m0 + tr) * DIN + tc * 4;
  int aw[8];
#pragma unroll
  for (int ph = 0; ph < 8; ++ph) {
    int r = tr + 16 * ph;
    int phys = (tc >> 1) ^ (r & 7);
    aw[ph] = r * 64 + phys * 8 + (tc & 1) * 4;
  }

  // B staging via DMA: regions of 8 rows x 128B, XOR chunk swizzle.
  int srow = lane >> 3;
  int schunk = (lane & 7) ^ srow;
  const f16* gb[4];
  const f16* lbb[4];
#pragma unroll
  for (int j = 0; j < 4; ++j) {
    int br = w * 32 + j * 8;
    gb[j] = wt + (size_t)(n0 + br + srow) * DIN + schunk * 8;
    lbb[j] = &Bs[__builtin_amdgcn_readfirstlane(br * 64)];
  }
  int xo0 = ((0 * 4 + lq) ^ (lr & 7)) * 8;
  int xo1 = ((1 * 4 + lq) ^ (lr & 7)) * 8;

  f32x4 zero = {0.f, 0.f, 0.f, 0.f};
  f32x4 acc[4][4];
#pragma unroll
  for (int i = 0; i < 4; ++i)
#pragma unroll
    for (int j = 0; j < 4; ++j) acc[i][j] = zero;

  for (int k0 = 0; k0 < DIN; k0 += 64) {
    __syncthreads();
#pragma unroll
    for (int j = 0; j < 4; ++j) gl_lds16(gb[j] + k0, lbb[j]);
#pragma unroll
    for (int ph = 0; ph < 8; ++ph) {
      float4 a = *(const float4*)(xg + (size_t)ph * 16 * DIN + k0);
      *(f16x4*)&As[aw[ph]] = pk4(a.x, a.y, a.z, a.w);
    }
    __syncthreads();
#pragma unroll
    for (int c = 0; c < 2; ++c) {
      int xo = c ? xo1 : xo0;
      f16x8 xf[4], wf[4];
#pragma unroll
      for (int i = 0; i < 4; ++i)
        xf[i] = *(const f16x8*)&As[(wm + i * 16 + lr) * 64 + xo];
#pragma unroll
      for (int i = 0; i < 4; ++i)
        wf[i] = *(const f16x8*)&Bs[(wn + i * 16 + lr) * 64 + xo];
      if (gemm == 2) {
#pragma unroll
        for (int i = 0; i < 4; ++i)
#pragma unroll
          for (int j = 0; j < 4; ++j)
            acc[i][j] = MFMA16(xf[i], wf[j], acc[i][j]);
      } else {
#pragma unroll
        for (int i = 0; i < 4; ++i)
#pragma unroll
          for (int j = 0; j < 4; ++j)
            acc[i][j] = MFMA16(wf[i], xf[j], acc[i][j]);
      }
    }
  }

  __syncthreads();  // all MFMA reads of As/Bs done before CT overwrite
  int b_ = m0 >> 11;
  int sl = m0 & 2047;

  if (gemm == 2) {
#pragma unroll
    for (int i = 0; i < 4; ++i) {
#pragma unroll
      for (int j = 0; j < 4; ++j) {
        int d = wn + j * 16 + lr;
        int lc = (wm >> 3) + i * 2 + (lq >> 1);
        int phys = lc ^ lr;
        *(f16x4*)&CT[d * 128 + phys * 8 + (lq & 1) * 4] =
            pk4(acc[i][j][0], acc[i][j][1], acc[i][j][2], acc[i][j][3]);
      }
    }
    __syncthreads();
    int tid16 = t & 15;
#pragma unroll
    for (int ph = 0; ph < 8; ++ph) {
      int d = ph * 16 + (t >> 4);
      int phys = tid16 ^ (d & 15);
      f16x8 vv = *(const f16x8*)&CT[d * 128 + phys * 8];
      int hgl = (n0 + d) >> 6, dd = (n0 + d) & 63;
      *(f16x8*)&Vt[(((size_t)b_ * NHEADS + hgl) * HDIM + dd) * SEQ + sl +
                   tid16 * 8] = vv;
    }
  } else {
    f16* O = gemm == 0 ? Qo : Ko;
    float sc = gemm == 0 ? C1 : 1.0f;
#pragma unroll
    for (int i = 0; i < 4; ++i) {
#pragma unroll
      for (int j = 0; j < 4; ++j) {
        int s = wm + j * 16 + lr;
        int lc = (wn >> 3) + i * 2 + (lq >> 1);
        int phys = lc ^ lr;
        *(f16x4*)&CT[s * 128 + phys * 8 + (lq & 1) * 4] =
            pk4(acc[i][j][0] * sc, acc[i][j][1] * sc, acc[i][j][2] * sc,
                acc[i][j][3] * sc);
      }
    }
    __syncthreads();
    int tid8 = t & 7;
    int hh = (t >> 3) & 1;
#pragma unroll
    for (int ph = 0; ph < 8; ++ph) {
      int s = ph * 16 + (t >> 4);
      int lc = hh * 8 + tid8;
      int phys = lc ^ (s & 15);
      f16x8 vv = *(const f16x8*)&CT[s * 128 + phys * 8];
      int hgl = (n0 >> 6) + hh;
      *(f16x8*)&O[(((size_t)b_ * NHEADS + hgl) * SEQ + sl + s) * HDIM +
                  tid8 * 8] = vv;
    }
  }
}

// ---------------------------------------------------------------------------
// flash_attn R9: 8 waves x 16 q-rows (was 4 x 32).  Same 128-row Q-tile, same
// LDS layout/swizzles, same R8 pipeline choreography — the ONLY variable is
// waves/SIMD 2 -> 4 (512 threads, LDS still 74 KB -> 2 blocks/CU = 16
// waves/CU).  Per-wave staging halves: 2 K-DMAs + 2 V-DMAs -> in-loop wait
// becomes vmcnt(2).
// ---------------------------------------------------------------------------
__global__ __launch_bounds__(512, 4) void flash_attn(
    const f16* __restrict__ Q, const f16* __restrict__ K,
    const f16* __restrict__ Vt, const float* __restrict__ mask,
    float* __restrict__ out) {
  __shared__ __attribute__((aligned(16))) f16 Ks[128 * 64];   // [k][d] swizzled
  __shared__ __attribute__((aligned(16))) f16 Vs[64 * 128];   // [d][k] swizzled
  __shared__ __attribute__((aligned(16))) f16 Ps[128 * 136];  // [q][k] padded
  __shared__ __attribute__((aligned(16))) float Ms[SEQ];      // mask row (8 KB)

  int bh = blockIdx.x, q0 = blockIdx.y * 128;
  int b = bh >> 3, h = bh & 7;
  int t = threadIdx.x, w = t >> 6, lane = t & 63;  // w in 0..7
  int lr = lane & 15, lq = lane >> 4;

  const f16* Qg = Q + (size_t)bh * SEQ * HDIM;
  const f16* Kg = K + (size_t)bh * SEQ * HDIM;
  const f16* Vg = Vt + (size_t)bh * HDIM * SEQ;
  const float* mg = mask + (size_t)b * SEQ;

  // Q fragments in registers: wave rows q0 + w*16 + lr (one 16-row strip)
  f16x8 qf[2];
#pragma unroll
  for (int c = 0; c < 2; ++c)
    qf[c] = *(const f16x8*)(Qg + (size_t)(q0 + w * 16 + lr) * HDIM + c * 32 +
                            lq * 8);

  // K staging: 2 regions of 8 rows x 128B per wave
  int krow = lane >> 3;
  int kchunk = (lane & 7) ^ krow;
  const f16* gk[2];
  const f16* gv[2];
  const f16* lk[2];
  const f16* lv[2];
#pragma unroll
  for (int j = 0; j < 2; ++j) {
    int kbr = w * 16 + j * 8;
    gk[j] = Kg + (size_t)(kbr + krow) * HDIM + kchunk * 8;
    lk[j] = &Ks[__builtin_amdgcn_readfirstlane(kbr * 64)];
    int vbr = w * 8 + j * 4;
    int vchunk = (lane & 15) ^ ((vbr + lq) & 15);
    gv[j] = Vg + (size_t)(vbr + lq) * SEQ + vchunk * 8;
    lv[j] = &Vs[__builtin_amdgcn_readfirstlane(vbr * 128)];
  }
  int xk0 = ((0 * 4 + lq) ^ (lr & 7)) * 8;
  int xk1 = ((1 * 4 + lq) ^ (lr & 7)) * 8;

  f32x4 zero = {0.f, 0.f, 0.f, 0.f};
  f32x4 acc[4];
#pragma unroll
  for (int i = 0; i < 4; ++i) acc[i] = zero;
  float lsum = 0.f;

  // ---- prologue: stage mask row + K0 + V0, drain, barrier
  {
    int c0 = w * 256;  // 256 floats per wave, one 1KB DMA
    gl_lds16(mg + c0 + lane * 4, &Ms[__builtin_amdgcn_readfirstlane(c0)]);
  }
#pragma unroll
  for (int j = 0; j < 2; ++j) {
    gl_lds16(gk[j], lk[j]);
    gl_lds16(gv[j], lv[j]);
  }
  asm volatile("s_waitcnt vmcnt(0)" ::: "memory");
  __builtin_amdgcn_sched_barrier(0);
  __builtin_amdgcn_s_barrier();
  __builtin_amdgcn_sched_barrier(0);

  for (int it = 0; it < 16; ++it) {
    int k0 = it * 128;

    // ---- S^T = K Q^T : D[m=k][n=q]; q=lane&15, k=lq*4+reg
    f32x4 s[8];
    __builtin_amdgcn_s_setprio(1);
#pragma unroll
    for (int nt = 0; nt < 8; ++nt) {
      f16x8 kf0 = *(const f16x8*)&Ks[(nt * 16 + lr) * 64 + xk0];
      f16x8 kf1 = *(const f16x8*)&Ks[(nt * 16 + lr) * 64 + xk1];
      s[nt] = MFMA16(kf0, qf[0], zero);
      s[nt] = MFMA16(kf1, qf[1], s[nt]);
    }
    __builtin_amdgcn_s_setprio(0);

    // my V(it) landed (vmcnt: only staging DMAs in flight) + everyone done
    // reading Ks(it)  => safe to overwrite Ks, and Vs(it) is valid for PV.
    asm volatile("s_waitcnt vmcnt(0)" ::: "memory");
    __builtin_amdgcn_sched_barrier(0);
    __builtin_amdgcn_s_barrier();
    __builtin_amdgcn_sched_barrier(0);
    if (it < 15) {
#pragma unroll
      for (int j = 0; j < 2; ++j)
        gl_lds16(gk[j] + (size_t)(k0 + 128) * HDIM, lk[j]);
    }

    // ---- p = exp2(s + mask*log2e); accumulate l per lane; pack -> Ps
#pragma unroll
    for (int nt = 0; nt < 8; ++nt) {
      float4 mk = *(const float4*)&Ms[k0 + nt * 16 + lq * 4];
      float p0 = fexp2(fmaf(mk.x, LOG2E, s[nt][0]));
      float p1 = fexp2(fmaf(mk.y, LOG2E, s[nt][1]));
      float p2 = fexp2(fmaf(mk.z, LOG2E, s[nt][2]));
      float p3 = fexp2(fmaf(mk.w, LOG2E, s[nt][3]));
      lsum += (p0 + p1) + (p2 + p3);
      *(f16x4*)&Ps[(w * 16 + lr) * 136 + nt * 16 + lq * 4] =
          pk4(p0, p1, p2, p3);
    }

    // ---- O += P V
    __builtin_amdgcn_s_setprio(1);
#pragma unroll
    for (int ks = 0; ks < 4; ++ks) {
      f16x8 ap = *(const f16x8*)&Ps[(w * 16 + lr) * 136 + ks * 32 + lq * 8];
#pragma unroll
      for (int dt = 0; dt < 4; ++dt) {
        f16x8 bv = *(const f16x8*)&Vs[(dt * 16 + lr) * 128 +
                                      (((ks * 4 + lq) ^ lr) * 8)];
        acc[dt] = MFMA16(ap, bv, acc[dt]);
      }
    }
    __builtin_amdgcn_s_setprio(0);

    if (it < 15) {
      // everyone done reading Vs(it) => safe to overwrite Vs
      __builtin_amdgcn_sched_barrier(0);
      __builtin_amdgcn_s_barrier();
      __builtin_amdgcn_sched_barrier(0);
#pragma unroll
      for (int j = 0; j < 2; ++j) gl_lds16(gv[j] + k0 + 128, lv[j]);
      // K(it+1) landed (2 V loads still in flight) -> Ks ready for next QKT
      asm volatile("s_waitcnt vmcnt(2)" ::: "memory");
      __builtin_amdgcn_sched_barrier(0);
      __builtin_amdgcn_s_barrier();
      __builtin_amdgcn_sched_barrier(0);
    }
  }

  // epilogue: l reduction + normalize + store
  {
    float l = lsum;
    l += __shfl_xor(l, 16);
    l += __shfl_xor(l, 32);
    float inv = 1.f / l;
    float iv[4];
#pragma unroll
    for (int r = 0; r < 4; ++r) iv[r] = __shfl(inv, lq * 4 + r);
#pragma unroll
    for (int dt = 0; dt < 4; ++dt) {
#pragma unroll
      for (int r = 0; r < 4; ++r) {
        int q = q0 + w * 16 + lq * 4 + r;
        int d = h * HDIM + dt * 16 + lr;
        out[((size_t)b * SEQ + q) * DOUT + d] = acc[dt][r] * iv[r];
      }
    }
  }
}

// ---------------------------------------------------------------------------
extern "C" void kernel_launch(void* const* d_in, const int* in_sizes, int n_in,
                              void* d_out, int out_size, void* d_ws,
                              size_t ws_size, hipStream_t stream) {
  const float* key = (const float*)d_in[0];
  const float* key_mask = (const float*)d_in[1];
  const float* query = (const float*)d_in[2];
  const float* value = (const float*)d_in[3];
  const float* wq = (const float*)d_in[4];
  const float* wk = (const float*)d_in[5];
  const float* wv = (const float*)d_in[6];
  float* out = (float*)d_out;

  char* ws = (char*)d_ws;
  f16* Qws = (f16*)(ws);              //  8.39 MB
  f16* Kws = (f16*)(ws + 8388608);    //  8.39 MB
  f16* Vtws = (f16*)(ws + 16777216);  //  8.39 MB
  f16* wT = (f16*)(ws + 25165824);    //  1.57 MB (total ~26.7 MB)

  prep_w<<<dim3(8, 8, 3), 256, 0, stream>>>(wq, wk, wv, wT);
  qkv_gemm<<<dim3(256, 1, 3), 256, 0, stream>>>(query, key, value, wT, Qws,
                                                Kws, Vtws);
  flash_attn<<<dim3(32, 16), 512, 0, stream>>>(Qws, Kws, Vtws, key_mask, out);
}

// Round 3
// 182.646 us; speedup vs baseline: 1.0131x; 1.0131x over previous
//
#include <hip/hip_runtime.h>

typedef _Float16 f16;
typedef f16 f16x8 __attribute__((ext_vector_type(8)));
typedef f16 f16x4 __attribute__((ext_vector_type(4)));
typedef f16 f16x2 __attribute__((ext_vector_type(2)));
typedef float f32x4 __attribute__((ext_vector_type(4)));
typedef float f32x16 __attribute__((ext_vector_type(16)));
typedef unsigned int u32;
typedef u32 u32x2 __attribute__((ext_vector_type(2)));
typedef u32 u32x4 __attribute__((ext_vector_type(4)));

#define MFMA16(a, b, c) __builtin_amdgcn_mfma_f32_16x16x32_f16(a, b, c, 0, 0, 0)
#define MFMA32(a, b, c) __builtin_amdgcn_mfma_f32_32x32x16_f16(a, b, c, 0, 0, 0)

#define BATCH 4
#define NHEADS 8
#define HDIM 64
#define SEQ 2048
#define DIN 512
#define DOUT 512
#define LOG2E 1.44269504f
#define C1 0.18033688f  // 0.125 * log2(e), folded into Q at qkv epilogue

__device__ __forceinline__ void gl_lds16(const void* g, const void* l) {
  __builtin_amdgcn_global_load_lds(
      (const __attribute__((address_space(1))) u32*)g,
      (__attribute__((address_space(3))) u32*)l, 16, 0, 0);
}

__device__ __forceinline__ float fexp2(float x) {
  float r;
  asm("v_exp_f32 %0, %1" : "=v"(r) : "v"(x));
  return r;
}

__device__ __forceinline__ u32 pk2u(float a, float b) {
  return __builtin_bit_cast(u32, __builtin_amdgcn_cvt_pkrtz(a, b));
}

__device__ __forceinline__ f16x2 pk2(float a, float b) {
  return __builtin_bit_cast(f16x2, __builtin_amdgcn_cvt_pkrtz(a, b));
}

__device__ __forceinline__ f16x4 pk4(float a, float b, float c, float d) {
  f16x2 u0 = pk2(a, b), u1 = pk2(c, d);
  f16x4 r;
  r[0] = u0[0]; r[1] = u0[1]; r[2] = u1[0]; r[3] = u1[1];
  return r;
}

// ---------------------------------------------------------------------------
// prep_w: transpose+cvt weights w[k][n] fp32 -> wT[n][k] f16.  (unchanged)
// ---------------------------------------------------------------------------
__global__ __launch_bounds__(256) void prep_w(
    const float* __restrict__ wq, const float* __restrict__ wk,
    const float* __restrict__ wv, f16* __restrict__ wT) {
  __shared__ float tile[64][65];
  const float* w = blockIdx.z == 0 ? wq : (blockIdx.z == 1 ? wk : wv);
  f16* out = wT + (size_t)blockIdx.z * DIN * DOUT;
  int k0 = blockIdx.x * 64, n0 = blockIdx.y * 64;
  int t = threadIdx.x;
  int c = t & 63, rb = t >> 6;
#pragma unroll
  for (int ph = 0; ph < 16; ++ph) {
    int r = ph * 4 + rb;
    tile[r][c] = w[(size_t)(k0 + r) * DOUT + n0 + c];
  }
  __syncthreads();
#pragma unroll
  for (int ph = 0; ph < 16; ++ph) {
    int n = ph * 4 + rb;
    out[(size_t)(n0 + n) * DIN + k0 + c] = (f16)tile[c][n];
  }
}

// ---------------------------------------------------------------------------
// qkv_gemm: unchanged (verified; R7 showed reg-prefetch spills here).
// ---------------------------------------------------------------------------
__global__ __launch_bounds__(256, 3) void qkv_gemm(
    const float* __restrict__ xq, const float* __restrict__ xk,
    const float* __restrict__ xv, const f16* __restrict__ wT,
    f16* __restrict__ Qo, f16* __restrict__ Ko, f16* __restrict__ Vt) {
  __shared__ __attribute__((aligned(16))) f16 smem[16384];  // 32 KB
  f16* As = smem;          // 128x64
  f16* Bs = smem + 8192;   // 128x64
  f16* CT = smem;          // epilogue: 128x128 (aliases As+Bs)

  int gemm = blockIdx.z;
  const float* x = gemm == 0 ? xq : (gemm == 1 ? xk : xv);
  const f16* wt = wT + (size_t)gemm * DIN * DOUT;
  int bx = blockIdx.x;
  int m0 = (bx & 63) * 128, n0 = (bx >> 6) * 128;
  int t = threadIdx.x, w = t >> 6, lane = t & 63;
  int lr = lane & 15, lq = lane >> 4;
  int wm = (w >> 1) * 64, wn = (w & 1) * 64;

  // A staging (fp32 -> f16 through regs): 16 threads/row, 8 row-phases.
  int tr = t >> 4, tc = t & 15;
  const float* xg = x + (size_t)(m0 + tr) * DIN + tc * 4;
  int aw[8];
#pragma unroll
  for (int ph = 0; ph < 8; ++ph) {
    int r = tr + 16 * ph;
    int phys = (tc >> 1) ^ (r & 7);
    aw[ph] = r * 64 + phys * 8 + (tc & 1) * 4;
  }

  // B staging via DMA: regions of 8 rows x 128B, XOR chunk swizzle.
  int srow = lane >> 3;
  int schunk = (lane & 7) ^ srow;
  const f16* gb[4];
  const f16* lbb[4];
#pragma unroll
  for (int j = 0; j < 4; ++j) {
    int br = w * 32 + j * 8;
    gb[j] = wt + (size_t)(n0 + br + srow) * DIN + schunk * 8;
    lbb[j] = &Bs[__builtin_amdgcn_readfirstlane(br * 64)];
  }
  int xo0 = ((0 * 4 + lq) ^ (lr & 7)) * 8;
  int xo1 = ((1 * 4 + lq) ^ (lr & 7)) * 8;

  f32x4 zero = {0.f, 0.f, 0.f, 0.f};
  f32x4 acc[4][4];
#pragma unroll
  for (int i = 0; i < 4; ++i)
#pragma unroll
    for (int j = 0; j < 4; ++j) acc[i][j] = zero;

  for (int k0 = 0; k0 < DIN; k0 += 64) {
    __syncthreads();
#pragma unroll
    for (int j = 0; j < 4; ++j) gl_lds16(gb[j] + k0, lbb[j]);
#pragma unroll
    for (int ph = 0; ph < 8; ++ph) {
      float4 a = *(const float4*)(xg + (size_t)ph * 16 * DIN + k0);
      *(f16x4*)&As[aw[ph]] = pk4(a.x, a.y, a.z, a.w);
    }
    __syncthreads();
#pragma unroll
    for (int c = 0; c < 2; ++c) {
      int xo = c ? xo1 : xo0;
      f16x8 xf[4], wf[4];
#pragma unroll
      for (int i = 0; i < 4; ++i)
        xf[i] = *(const f16x8*)&As[(wm + i * 16 + lr) * 64 + xo];
#pragma unroll
      for (int i = 0; i < 4; ++i)
        wf[i] = *(const f16x8*)&Bs[(wn + i * 16 + lr) * 64 + xo];
      if (gemm == 2) {
#pragma unroll
        for (int i = 0; i < 4; ++i)
#pragma unroll
          for (int j = 0; j < 4; ++j)
            acc[i][j] = MFMA16(xf[i], wf[j], acc[i][j]);
      } else {
#pragma unroll
        for (int i = 0; i < 4; ++i)
#pragma unroll
          for (int j = 0; j < 4; ++j)
            acc[i][j] = MFMA16(wf[i], xf[j], acc[i][j]);
      }
    }
  }

  __syncthreads();  // all MFMA reads of As/Bs done before CT overwrite
  int b_ = m0 >> 11;
  int sl = m0 & 2047;

  if (gemm == 2) {
#pragma unroll
    for (int i = 0; i < 4; ++i) {
#pragma unroll
      for (int j = 0; j < 4; ++j) {
        int d = wn + j * 16 + lr;
        int lc = (wm >> 3) + i * 2 + (lq >> 1);
        int phys = lc ^ lr;
        *(f16x4*)&CT[d * 128 + phys * 8 + (lq & 1) * 4] =
            pk4(acc[i][j][0], acc[i][j][1], acc[i][j][2], acc[i][j][3]);
      }
    }
    __syncthreads();
    int tid16 = t & 15;
#pragma unroll
    for (int ph = 0; ph < 8; ++ph) {
      int d = ph * 16 + (t >> 4);
      int phys = tid16 ^ (d & 15);
      f16x8 vv = *(const f16x8*)&CT[d * 128 + phys * 8];
      int hgl = (n0 + d) >> 6, dd = (n0 + d) & 63;
      *(f16x8*)&Vt[(((size_t)b_ * NHEADS + hgl) * HDIM + dd) * SEQ + sl +
                   tid16 * 8] = vv;
    }
  } else {
    f16* O = gemm == 0 ? Qo : Ko;
    float sc = gemm == 0 ? C1 : 1.0f;
#pragma unroll
    for (int i = 0; i < 4; ++i) {
#pragma unroll
      for (int j = 0; j < 4; ++j) {
        int s = wm + j * 16 + lr;
        int lc = (wn >> 3) + i * 2 + (lq >> 1);
        int phys = lc ^ lr;
        *(f16x4*)&CT[s * 128 + phys * 8 + (lq & 1) * 4] =
            pk4(acc[i][j][0] * sc, acc[i][j][1] * sc, acc[i][j][2] * sc,
                acc[i][j][3] * sc);
      }
    }
    __syncthreads();
    int tid8 = t & 7;
    int hh = (t >> 3) & 1;
#pragma unroll
    for (int ph = 0; ph < 8; ++ph) {
      int s = ph * 16 + (t >> 4);
      int lc = hh * 8 + tid8;
      int phys = lc ^ (s & 15);
      f16x8 vv = *(const f16x8*)&CT[s * 128 + phys * 8];
      int hgl = (n0 >> 6) + hh;
      *(f16x8*)&O[(((size_t)b_ * NHEADS + hgl) * SEQ + sl + s) * HDIM +
                  tid8 * 8] = vv;
    }
  }
}

// ---------------------------------------------------------------------------
// flash_attn R10: 32x32x16 MFMA + in-register P (T12).  4 waves x 32 q-rows.
//  - S^T = K.Q^T per 32k-tile: lane holds P[q=lane&31][k=(r&3)+8(r>>2)+4hf].
//  - softmax per nt-tile interleaved with QK^T (exp overlaps MFMA issue).
//  - P -> PV A-frag fully in-register: cvt_pkrtz pairs + 2 permlane32_swap
//    per k-step (one swap yields words 0&2, the other 1&3).  Ps LDS GONE.
//  - kf/bv LDS reads amortize over 2x FLOPs vs 16x16 (32 q-rows/wave).
//  - mask via LDS broadcast reads; l-normalization via 128B scratch in Ms.
//  - R8/R9 barrier+counted-vmcnt choreography verbatim (vmcnt(4) in-loop).
// LDS: Ks 16K + Vs 16K + Ms 8K = 40 KB.
// ---------------------------------------------------------------------------
__global__ __launch_bounds__(256, 2) void flash_attn(
    const f16* __restrict__ Q, const f16* __restrict__ K,
    const f16* __restrict__ Vt, const float* __restrict__ mask,
    float* __restrict__ out) {
  __shared__ __attribute__((aligned(16))) f16 Ks[128 * 64];   // [k][d] swizzled
  __shared__ __attribute__((aligned(16))) f16 Vs[64 * 128];   // [d][k] swizzled
  __shared__ __attribute__((aligned(16))) float Ms[SEQ];      // mask row (8 KB)

  int bh = blockIdx.x, q0 = blockIdx.y * 128;
  int b = bh >> 3, h = bh & 7;
  int t = threadIdx.x, w = t >> 6, lane = t & 63;  // w in 0..3
  int lr = lane & 15, lq = lane >> 4;
  int l5 = lane & 31, hf = lane >> 5;

  const f16* Qg = Q + (size_t)bh * SEQ * HDIM;
  const f16* Kg = K + (size_t)bh * SEQ * HDIM;
  const f16* Vg = Vt + (size_t)bh * HDIM * SEQ;
  const float* mg = mask + (size_t)b * SEQ;

  // ---- staging pointers: K 4 regions of 8 rows x 128B; V 4 regions of 4x256B
  int krow = lane >> 3;
  int kchunk = (lane & 7) ^ krow;
  const f16* gk[4];
  const f16* gv[4];
  const f16* lk[4];
  const f16* lv[4];
#pragma unroll
  for (int j = 0; j < 4; ++j) {
    int kbr = w * 32 + j * 8;
    gk[j] = Kg + (size_t)(kbr + krow) * HDIM + kchunk * 8;
    lk[j] = &Ks[__builtin_amdgcn_readfirstlane(kbr * 64)];
    int vbr = w * 16 + j * 4;
    int vchunk = (lane & 15) ^ ((vbr + lq) & 15);
    gv[j] = Vg + (size_t)(vbr + lq) * SEQ + vchunk * 8;
    lv[j] = &Vs[__builtin_amdgcn_readfirstlane(vbr * 128)];
  }

  // ---- prologue: stage mask + K0 + V0 first (DMA), then Q frags (global)
  {
    int c0 = w * 512;  // 512 floats per wave, two 1KB DMAs
    gl_lds16(mg + c0 + lane * 4, &Ms[__builtin_amdgcn_readfirstlane(c0)]);
    gl_lds16(mg + c0 + 256 + lane * 4,
             &Ms[__builtin_amdgcn_readfirstlane(c0 + 256)]);
  }
#pragma unroll
  for (int j = 0; j < 4; ++j) {
    gl_lds16(gk[j], lk[j]);
    gl_lds16(gv[j], lv[j]);
  }

  // Q fragments (B-operand, rows q = q0 + w*32 + l5): qf[ds] covers
  // d = ds*16 + hf*8 + j
  f16x8 qf[4];
#pragma unroll
  for (int ds = 0; ds < 4; ++ds)
    qf[ds] = *(const f16x8*)(Qg + (size_t)(q0 + w * 32 + l5) * HDIM + ds * 16 +
                             hf * 8);

  f32x16 acc[2];
#pragma unroll
  for (int dt = 0; dt < 2; ++dt)
#pragma unroll
    for (int i = 0; i < 16; ++i) acc[dt][i] = 0.f;
  float lsum = 0.f;

  asm volatile("s_waitcnt vmcnt(0)" ::: "memory");
  __builtin_amdgcn_sched_barrier(0);
  __builtin_amdgcn_s_barrier();
  __builtin_amdgcn_sched_barrier(0);

  for (int it = 0; it < 16; ++it) {
    int k0 = it * 128;
    u32 pk_[4][4][2];  // [nt][g=r>>2][word]

    // ---- S^T = K Q^T (per 32k nt-tile) + softmax interleaved
#pragma unroll
    for (int nt = 0; nt < 4; ++nt) {
      f32x16 s = {0.f, 0.f, 0.f, 0.f, 0.f, 0.f, 0.f, 0.f,
                  0.f, 0.f, 0.f, 0.f, 0.f, 0.f, 0.f, 0.f};
      __builtin_amdgcn_s_setprio(1);
#pragma unroll
      for (int ds = 0; ds < 4; ++ds) {
        f16x8 kf = *(const f16x8*)&Ks[(nt * 32 + l5) * 64 +
                                      (((ds * 2 + hf) ^ (l5 & 7)) * 8)];
        s = MFMA32(kf, qf[ds], s);
      }
      __builtin_amdgcn_s_setprio(0);
      // softmax for this nt: p = exp2(s + mask*log2e); k = k0 + nt*32 +
      // run*8 + 4*hf + i  (broadcast LDS reads, free)
#pragma unroll
      for (int run = 0; run < 4; ++run) {
        float4 mk = *(const float4*)&Ms[k0 + nt * 32 + run * 8 + 4 * hf];
        float p0 = fexp2(fmaf(mk.x, LOG2E, s[run * 4 + 0]));
        float p1 = fexp2(fmaf(mk.y, LOG2E, s[run * 4 + 1]));
        float p2 = fexp2(fmaf(mk.z, LOG2E, s[run * 4 + 2]));
        float p3 = fexp2(fmaf(mk.w, LOG2E, s[run * 4 + 3]));
        lsum += (p0 + p1) + (p2 + p3);
        pk_[nt][run][0] = pk2u(p0, p1);
        pk_[nt][run][1] = pk2u(p2, p3);
      }
    }

    // V(it) landed + all waves done reading Ks(it)
    asm volatile("s_waitcnt vmcnt(0)" ::: "memory");
    __builtin_amdgcn_sched_barrier(0);
    __builtin_amdgcn_s_barrier();
    __builtin_amdgcn_sched_barrier(0);
    if (it < 15) {
#pragma unroll
      for (int j = 0; j < 4; ++j)
        gl_lds16(gk[j] + (size_t)(k0 + 128) * HDIM, lk[j]);
    }

    // ---- O += P V : ap assembled in-register via permlane32_swap
    __builtin_amdgcn_s_setprio(1);
#pragma unroll
    for (int ks = 0; ks < 8; ++ks) {
      const int nt = ks >> 1;
      const int ge = 2 * (ks & 1);      // g for hf=0 lanes
      const int go = 2 * (ks & 1) + 1;  // g for hf=1 lanes
      u32x2 r0 = __builtin_amdgcn_permlane32_swap(pk_[nt][ge][0],
                                                  pk_[nt][go][0], false, false);
      u32x2 r1 = __builtin_amdgcn_permlane32_swap(pk_[nt][ge][1],
                                                  pk_[nt][go][1], false, false);
      u32x4 apw = {r0[0], r1[0], r0[1], r1[1]};
      f16x8 ap = __builtin_bit_cast(f16x8, apw);
#pragma unroll
      for (int dt = 0; dt < 2; ++dt) {
        f16x8 bv = *(const f16x8*)&Vs[(dt * 32 + l5) * 128 +
                                      (((ks * 2 + hf) ^ (l5 & 15)) * 8)];
        acc[dt] = MFMA32(ap, bv, acc[dt]);
      }
    }
    __builtin_amdgcn_s_setprio(0);

    if (it < 15) {
      // all waves done reading Vs(it)
      __builtin_amdgcn_sched_barrier(0);
      __builtin_amdgcn_s_barrier();
      __builtin_amdgcn_sched_barrier(0);
#pragma unroll
      for (int j = 0; j < 4; ++j) gl_lds16(gv[j] + k0 + 128, lv[j]);
      // K(it+1) landed (4 V loads still in flight)
      asm volatile("s_waitcnt vmcnt(4)" ::: "memory");
      __builtin_amdgcn_sched_barrier(0);
      __builtin_amdgcn_s_barrier();
      __builtin_amdgcn_sched_barrier(0);
    }
  }

  // ---- epilogue: cross-half l sum, redistribute inv via Ms[0:128) scratch
  // (safe: last-iter mask reads touch Ms[1920:2048) only; region is
  // wave-private so no barrier needed)
  float l = lsum + __shfl_xor(lsum, 32);
  float inv = 1.f / l;
  Ms[w * 32 + l5] = inv;  // lanes l5 / l5+32 write same value
  asm volatile("s_waitcnt lgkmcnt(0)" ::: "memory");
  __builtin_amdgcn_sched_barrier(0);
  float ivq[16];
#pragma unroll
  for (int r = 0; r < 16; ++r)
    ivq[r] = Ms[w * 32 + (r & 3) + 8 * (r >> 2) + 4 * hf];

#pragma unroll
  for (int dt = 0; dt < 2; ++dt) {
#pragma unroll
    for (int r = 0; r < 16; ++r) {
      int q = q0 + w * 32 + (r & 3) + 8 * (r >> 2) + 4 * hf;
      int d = h * HDIM + dt * 32 + l5;
      out[((size_t)b * SEQ + q) * DOUT + d] = acc[dt][r] * ivq[r];
    }
  }
}

// ---------------------------------------------------------------------------
extern "C" void kernel_launch(void* const* d_in, const int* in_sizes, int n_in,
                              void* d_out, int out_size, void* d_ws,
                              size_t ws_size, hipStream_t stream) {
  const float* key = (const float*)d_in[0];
  const float* key_mask = (const float*)d_in[1];
  const float* query = (const float*)d_in[2];
  const float* value = (const float*)d_in[3];
  const float* wq = (const float*)d_in[4];
  const float* wk = (const float*)d_in[5];
  const float* wv = (const float*)d_in[6];
  float* out = (float*)d_out;

  char* ws = (char*)d_ws;
  f16* Qws = (f16*)(ws);              //  8.39 MB
  f16* Kws = (f16*)(ws + 8388608);    //  8.39 MB
  f16* Vtws = (f16*)(ws + 16777216);  //  8.39 MB
  f16* wT = (f16*)(ws + 25165824);    //  1.57 MB (total ~26.7 MB)

  prep_w<<<dim3(8, 8, 3), 256, 0, stream>>>(wq, wk, wv, wT);
  qkv_gemm<<<dim3(256, 1, 3), 256, 0, stream>>>(query, key, value, wT, Qws,
                                                Kws, Vtws);
  flash_attn<<<dim3(32, 16), 256, 0, stream>>>(Qws, Kws, Vtws, key_mask, out);
}

// Round 4
// 180.072 us; speedup vs baseline: 1.0276x; 1.0143x over previous
//
#include <hip/hip_runtime.h>

typedef _Float16 f16;
typedef f16 f16x8 __attribute__((ext_vector_type(8)));
typedef f16 f16x4 __attribute__((ext_vector_type(4)));
typedef f16 f16x2 __attribute__((ext_vector_type(2)));
typedef float f32x4 __attribute__((ext_vector_type(4)));
typedef float f32x16 __attribute__((ext_vector_type(16)));
typedef unsigned int u32;
typedef u32 u32x2 __attribute__((ext_vector_type(2)));
typedef u32 u32x4 __attribute__((ext_vector_type(4)));

#define MFMA16(a, b, c) __builtin_amdgcn_mfma_f32_16x16x32_f16(a, b, c, 0, 0, 0)
#define MFMA32(a, b, c) __builtin_amdgcn_mfma_f32_32x32x16_f16(a, b, c, 0, 0, 0)

#define BATCH 4
#define NHEADS 8
#define HDIM 64
#define SEQ 2048
#define DIN 512
#define DOUT 512
#define LOG2E 1.44269504f
#define C1 0.18033688f  // 0.125 * log2(e), folded into Q at qkv epilogue

__device__ __forceinline__ void gl_lds16(const void* g, const void* l) {
  __builtin_amdgcn_global_load_lds(
      (const __attribute__((address_space(1))) u32*)g,
      (__attribute__((address_space(3))) u32*)l, 16, 0, 0);
}

__device__ __forceinline__ float fexp2(float x) {
  float r;
  asm("v_exp_f32 %0, %1" : "=v"(r) : "v"(x));
  return r;
}

__device__ __forceinline__ u32 pk2u(float a, float b) {
  return __builtin_bit_cast(u32, __builtin_amdgcn_cvt_pkrtz(a, b));
}

__device__ __forceinline__ f16x2 pk2(float a, float b) {
  return __builtin_bit_cast(f16x2, __builtin_amdgcn_cvt_pkrtz(a, b));
}

__device__ __forceinline__ f16x4 pk4(float a, float b, float c, float d) {
  f16x2 u0 = pk2(a, b), u1 = pk2(c, d);
  f16x4 r;
  r[0] = u0[0]; r[1] = u0[1]; r[2] = u1[0]; r[3] = u1[1];
  return r;
}

// ---------------------------------------------------------------------------
// prep_w: transpose+cvt weights w[k][n] fp32 -> wT[n][k] f16.  (unchanged)
// ---------------------------------------------------------------------------
__global__ __launch_bounds__(256) void prep_w(
    const float* __restrict__ wq, const float* __restrict__ wk,
    const float* __restrict__ wv, f16* __restrict__ wT) {
  __shared__ float tile[64][65];
  const float* w = blockIdx.z == 0 ? wq : (blockIdx.z == 1 ? wk : wv);
  f16* out = wT + (size_t)blockIdx.z * DIN * DOUT;
  int k0 = blockIdx.x * 64, n0 = blockIdx.y * 64;
  int t = threadIdx.x;
  int c = t & 63, rb = t >> 6;
#pragma unroll
  for (int ph = 0; ph < 16; ++ph) {
    int r = ph * 4 + rb;
    tile[r][c] = w[(size_t)(k0 + r) * DOUT + n0 + c];
  }
  __syncthreads();
#pragma unroll
  for (int ph = 0; ph < 16; ++ph) {
    int n = ph * 4 + rb;
    out[(size_t)(n0 + n) * DIN + k0 + c] = (f16)tile[c][n];
  }
}

// ---------------------------------------------------------------------------
// qkv_gemm: unchanged (verified; R7 showed reg-prefetch spills here).
// ---------------------------------------------------------------------------
__global__ __launch_bounds__(256, 3) void qkv_gemm(
    const float* __restrict__ xq, const float* __restrict__ xk,
    const float* __restrict__ xv, const f16* __restrict__ wT,
    f16* __restrict__ Qo, f16* __restrict__ Ko, f16* __restrict__ Vt) {
  __shared__ __attribute__((aligned(16))) f16 smem[16384];  // 32 KB
  f16* As = smem;          // 128x64
  f16* Bs = smem + 8192;   // 128x64
  f16* CT = smem;          // epilogue: 128x128 (aliases As+Bs)

  int gemm = blockIdx.z;
  const float* x = gemm == 0 ? xq : (gemm == 1 ? xk : xv);
  const f16* wt = wT + (size_t)gemm * DIN * DOUT;
  int bx = blockIdx.x;
  int m0 = (bx & 63) * 128, n0 = (bx >> 6) * 128;
  int t = threadIdx.x, w = t >> 6, lane = t & 63;
  int lr = lane & 15, lq = lane >> 4;
  int wm = (w >> 1) * 64, wn = (w & 1) * 64;

  // A staging (fp32 -> f16 through regs): 16 threads/row, 8 row-phases.
  int tr = t >> 4, tc = t & 15;
  const float* xg = x + (size_t)(m0 + tr) * DIN + tc * 4;
  int aw[8];
#pragma unroll
  for (int ph = 0; ph < 8; ++ph) {
    int r = tr + 16 * ph;
    int phys = (tc >> 1) ^ (r & 7);
    aw[ph] = r * 64 + phys * 8 + (tc & 1) * 4;
  }

  // B staging via DMA: regions of 8 rows x 128B, XOR chunk swizzle.
  int srow = lane >> 3;
  int schunk = (lane & 7) ^ srow;
  const f16* gb[4];
  const f16* lbb[4];
#pragma unroll
  for (int j = 0; j < 4; ++j) {
    int br = w * 32 + j * 8;
    gb[j] = wt + (size_t)(n0 + br + srow) * DIN + schunk * 8;
    lbb[j] = &Bs[__builtin_amdgcn_readfirstlane(br * 64)];
  }
  int xo0 = ((0 * 4 + lq) ^ (lr & 7)) * 8;
  int xo1 = ((1 * 4 + lq) ^ (lr & 7)) * 8;

  f32x4 zero = {0.f, 0.f, 0.f, 0.f};
  f32x4 acc[4][4];
#pragma unroll
  for (int i = 0; i < 4; ++i)
#pragma unroll
    for (int j = 0; j < 4; ++j) acc[i][j] = zero;

  for (int k0 = 0; k0 < DIN; k0 += 64) {
    __syncthreads();
#pragma unroll
    for (int j = 0; j < 4; ++j) gl_lds16(gb[j] + k0, lbb[j]);
#pragma unroll
    for (int ph = 0; ph < 8; ++ph) {
      float4 a = *(const float4*)(xg + (size_t)ph * 16 * DIN + k0);
      *(f16x4*)&As[aw[ph]] = pk4(a.x, a.y, a.z, a.w);
    }
    __syncthreads();
#pragma unroll
    for (int c = 0; c < 2; ++c) {
      int xo = c ? xo1 : xo0;
      f16x8 xf[4], wf[4];
#pragma unroll
      for (int i = 0; i < 4; ++i)
        xf[i] = *(const f16x8*)&As[(wm + i * 16 + lr) * 64 + xo];
#pragma unroll
      for (int i = 0; i < 4; ++i)
        wf[i] = *(const f16x8*)&Bs[(wn + i * 16 + lr) * 64 + xo];
      if (gemm == 2) {
#pragma unroll
        for (int i = 0; i < 4; ++i)
#pragma unroll
          for (int j = 0; j < 4; ++j)
            acc[i][j] = MFMA16(xf[i], wf[j], acc[i][j]);
      } else {
#pragma unroll
        for (int i = 0; i < 4; ++i)
#pragma unroll
          for (int j = 0; j < 4; ++j)
            acc[i][j] = MFMA16(wf[i], xf[j], acc[i][j]);
      }
    }
  }

  __syncthreads();  // all MFMA reads of As/Bs done before CT overwrite
  int b_ = m0 >> 11;
  int sl = m0 & 2047;

  if (gemm == 2) {
#pragma unroll
    for (int i = 0; i < 4; ++i) {
#pragma unroll
      for (int j = 0; j < 4; ++j) {
        int d = wn + j * 16 + lr;
        int lc = (wm >> 3) + i * 2 + (lq >> 1);
        int phys = lc ^ lr;
        *(f16x4*)&CT[d * 128 + phys * 8 + (lq & 1) * 4] =
            pk4(acc[i][j][0], acc[i][j][1], acc[i][j][2], acc[i][j][3]);
      }
    }
    __syncthreads();
    int tid16 = t & 15;
#pragma unroll
    for (int ph = 0; ph < 8; ++ph) {
      int d = ph * 16 + (t >> 4);
      int phys = tid16 ^ (d & 15);
      f16x8 vv = *(const f16x8*)&CT[d * 128 + phys * 8];
      int hgl = (n0 + d) >> 6, dd = (n0 + d) & 63;
      *(f16x8*)&Vt[(((size_t)b_ * NHEADS + hgl) * HDIM + dd) * SEQ + sl +
                   tid16 * 8] = vv;
    }
  } else {
    f16* O = gemm == 0 ? Qo : Ko;
    float sc = gemm == 0 ? C1 : 1.0f;
#pragma unroll
    for (int i = 0; i < 4; ++i) {
#pragma unroll
      for (int j = 0; j < 4; ++j) {
        int s = wm + j * 16 + lr;
        int lc = (wn >> 3) + i * 2 + (lq >> 1);
        int phys = lc ^ lr;
        *(f16x4*)&CT[s * 128 + phys * 8 + (lq & 1) * 4] =
            pk4(acc[i][j][0] * sc, acc[i][j][1] * sc, acc[i][j][2] * sc,
                acc[i][j][3] * sc);
      }
    }
    __syncthreads();
    int tid8 = t & 7;
    int hh = (t >> 3) & 1;
#pragma unroll
    for (int ph = 0; ph < 8; ++ph) {
      int s = ph * 16 + (t >> 4);
      int lc = hh * 8 + tid8;
      int phys = lc ^ (s & 15);
      f16x8 vv = *(const f16x8*)&CT[s * 128 + phys * 8];
      int hgl = (n0 >> 6) + hh;
      *(f16x8*)&O[(((size_t)b_ * NHEADS + hgl) * SEQ + sl + s) * HDIM +
                  tid8 * 8] = vv;
    }
  }
}

// ---------------------------------------------------------------------------
// flash_attn R11: R10 + double-buffered Ks/Vs -> ONE barrier + ONE vmcnt per
// iteration (was 3 barriers + 2 vmcnt(0) drains).  Per iter: issue all 8
// DMAs for tile t+1 into buf^1 at iter start (buf^1 last read in iter t-1,
// protected by the end-of-iter barrier), compute QKT+softmax+PV entirely
// from buf with no mid barrier, then vmcnt(0)+s_barrier at iter end.  DMA
// latency hides under a full iteration of compute.  Compute bodies, T12
// in-register P, swizzles unchanged from R10.
// LDS: Ks 32K + Vs 32K + Ms 8K = 72 KB -> still 2 blocks/CU.
// ---------------------------------------------------------------------------
__global__ __launch_bounds__(256, 2) void flash_attn(
    const f16* __restrict__ Q, const f16* __restrict__ K,
    const f16* __restrict__ Vt, const float* __restrict__ mask,
    float* __restrict__ out) {
  __shared__ __attribute__((aligned(16))) f16 Ks[2 * 128 * 64];  // 32 KB
  __shared__ __attribute__((aligned(16))) f16 Vs[2 * 64 * 128];  // 32 KB
  __shared__ __attribute__((aligned(16))) float Ms[SEQ];         // 8 KB

  int bh = blockIdx.x, q0 = blockIdx.y * 128;
  int b = bh >> 3, h = bh & 7;
  int t = threadIdx.x, w = t >> 6, lane = t & 63;  // w in 0..3
  int lr = lane & 15, lq = lane >> 4;
  int l5 = lane & 31, hf = lane >> 5;

  const f16* Qg = Q + (size_t)bh * SEQ * HDIM;
  const f16* Kg = K + (size_t)bh * SEQ * HDIM;
  const f16* Vg = Vt + (size_t)bh * HDIM * SEQ;
  const float* mg = mask + (size_t)b * SEQ;

  // ---- staging pointers: K 4 regions of 8 rows x 128B; V 4 regions of 4x256B
  int krow = lane >> 3;
  int kchunk = (lane & 7) ^ krow;
  const f16* gk[4];
  const f16* gv[4];
  const f16* lk[4];
  const f16* lv[4];
#pragma unroll
  for (int j = 0; j < 4; ++j) {
    int kbr = w * 32 + j * 8;
    gk[j] = Kg + (size_t)(kbr + krow) * HDIM + kchunk * 8;
    lk[j] = &Ks[__builtin_amdgcn_readfirstlane(kbr * 64)];
    int vbr = w * 16 + j * 4;
    int vchunk = (lane & 15) ^ ((vbr + lq) & 15);
    gv[j] = Vg + (size_t)(vbr + lq) * SEQ + vchunk * 8;
    lv[j] = &Vs[__builtin_amdgcn_readfirstlane(vbr * 128)];
  }

  // ---- prologue: stage mask + K0 + V0 into buf0 (DMA), then Q frags
  {
    int c0 = w * 512;  // 512 floats per wave, two 1KB DMAs
    gl_lds16(mg + c0 + lane * 4, &Ms[__builtin_amdgcn_readfirstlane(c0)]);
    gl_lds16(mg + c0 + 256 + lane * 4,
             &Ms[__builtin_amdgcn_readfirstlane(c0 + 256)]);
  }
#pragma unroll
  for (int j = 0; j < 4; ++j) {
    gl_lds16(gk[j], lk[j]);
    gl_lds16(gv[j], lv[j]);
  }

  // Q fragments (B-operand, rows q = q0 + w*32 + l5): qf[ds] covers
  // d = ds*16 + hf*8 + j
  f16x8 qf[4];
#pragma unroll
  for (int ds = 0; ds < 4; ++ds)
    qf[ds] = *(const f16x8*)(Qg + (size_t)(q0 + w * 32 + l5) * HDIM + ds * 16 +
                             hf * 8);

  f32x16 acc[2];
#pragma unroll
  for (int dt = 0; dt < 2; ++dt)
#pragma unroll
    for (int i = 0; i < 16; ++i) acc[dt][i] = 0.f;
  float lsum = 0.f;

  asm volatile("s_waitcnt vmcnt(0)" ::: "memory");
  __builtin_amdgcn_sched_barrier(0);
  __builtin_amdgcn_s_barrier();
  __builtin_amdgcn_sched_barrier(0);

  for (int it = 0; it < 16; ++it) {
    int p = it & 1;
    int k0 = it * 128;
    const f16* Kb = &Ks[p * 8192];
    const f16* Vb = &Vs[p * 8192];

    // ---- issue prefetch of tile t+1 into buf^1 (read-done via last barrier)
    if (it < 15) {
      int pn = p ^ 1;
#pragma unroll
      for (int j = 0; j < 4; ++j) {
        gl_lds16(gk[j] + (size_t)(k0 + 128) * HDIM, lk[j] + pn * 8192);
        gl_lds16(gv[j] + k0 + 128, lv[j] + pn * 8192);
      }
    }

    u32 pk_[4][4][2];  // [nt][g=r>>2][word]

    // ---- S^T = K Q^T (per 32k nt-tile) + softmax interleaved
#pragma unroll
    for (int nt = 0; nt < 4; ++nt) {
      f32x16 s = {0.f, 0.f, 0.f, 0.f, 0.f, 0.f, 0.f, 0.f,
                  0.f, 0.f, 0.f, 0.f, 0.f, 0.f, 0.f, 0.f};
      __builtin_amdgcn_s_setprio(1);
#pragma unroll
      for (int ds = 0; ds < 4; ++ds) {
        f16x8 kf = *(const f16x8*)&Kb[(nt * 32 + l5) * 64 +
                                      (((ds * 2 + hf) ^ (l5 & 7)) * 8)];
        s = MFMA32(kf, qf[ds], s);
      }
      __builtin_amdgcn_s_setprio(0);
      // softmax for this nt: p = exp2(s + mask*log2e); k = k0 + nt*32 +
      // run*8 + 4*hf + i  (broadcast LDS reads, free)
#pragma unroll
      for (int run = 0; run < 4; ++run) {
        float4 mk = *(const float4*)&Ms[k0 + nt * 32 + run * 8 + 4 * hf];
        float p0 = fexp2(fmaf(mk.x, LOG2E, s[run * 4 + 0]));
        float p1 = fexp2(fmaf(mk.y, LOG2E, s[run * 4 + 1]));
        float p2 = fexp2(fmaf(mk.z, LOG2E, s[run * 4 + 2]));
        float p3 = fexp2(fmaf(mk.w, LOG2E, s[run * 4 + 3]));
        lsum += (p0 + p1) + (p2 + p3);
        pk_[nt][run][0] = pk2u(p0, p1);
        pk_[nt][run][1] = pk2u(p2, p3);
      }
    }

    // ---- O += P V : ap assembled in-register via permlane32_swap
    __builtin_amdgcn_s_setprio(1);
#pragma unroll
    for (int ks = 0; ks < 8; ++ks) {
      const int nt = ks >> 1;
      const int ge = 2 * (ks & 1);      // g for hf=0 lanes
      const int go = 2 * (ks & 1) + 1;  // g for hf=1 lanes
      u32x2 r0 = __builtin_amdgcn_permlane32_swap(pk_[nt][ge][0],
                                                  pk_[nt][go][0], false, false);
      u32x2 r1 = __builtin_amdgcn_permlane32_swap(pk_[nt][ge][1],
                                                  pk_[nt][go][1], false, false);
      u32x4 apw = {r0[0], r1[0], r0[1], r1[1]};
      f16x8 ap = __builtin_bit_cast(f16x8, apw);
#pragma unroll
      for (int dt = 0; dt < 2; ++dt) {
        f16x8 bv = *(const f16x8*)&Vb[(dt * 32 + l5) * 128 +
                                      (((ks * 2 + hf) ^ (l5 & 15)) * 8)];
        acc[dt] = MFMA32(ap, bv, acc[dt]);
      }
    }
    __builtin_amdgcn_s_setprio(0);

    // ---- single end-of-iter sync: own DMAs (issued at iter start) landed;
    // barrier => all waves' DMAs landed + all reads of buf done.
    asm volatile("s_waitcnt vmcnt(0)" ::: "memory");
    __builtin_amdgcn_sched_barrier(0);
    __builtin_amdgcn_s_barrier();
    __builtin_amdgcn_sched_barrier(0);
  }

  // ---- epilogue: cross-half l sum, redistribute inv via Ms[0:128) scratch
  // (safe: last-iter mask reads touch Ms[1920:2048) only; region is
  // wave-private so no barrier needed)
  float l = lsum + __shfl_xor(lsum, 32);
  float inv = 1.f / l;
  Ms[w * 32 + l5] = inv;  // lanes l5 / l5+32 write same value
  asm volatile("s_waitcnt lgkmcnt(0)" ::: "memory");
  __builtin_amdgcn_sched_barrier(0);
  float ivq[16];
#pragma unroll
  for (int r = 0; r < 16; ++r)
    ivq[r] = Ms[w * 32 + (r & 3) + 8 * (r >> 2) + 4 * hf];

#pragma unroll
  for (int dt = 0; dt < 2; ++dt) {
#pragma unroll
    for (int r = 0; r < 16; ++r) {
      int q = q0 + w * 32 + (r & 3) + 8 * (r >> 2) + 4 * hf;
      int d = h * HDIM + dt * 32 + l5;
      out[((size_t)b * SEQ + q) * DOUT + d] = acc[dt][r] * ivq[r];
    }
  }
}

// ---------------------------------------------------------------------------
extern "C" void kernel_launch(void* const* d_in, const int* in_sizes, int n_in,
                              void* d_out, int out_size, void* d_ws,
                              size_t ws_size, hipStream_t stream) {
  const float* key = (const float*)d_in[0];
  const float* key_mask = (const float*)d_in[1];
  const float* query = (const float*)d_in[2];
  const float* value = (const float*)d_in[3];
  const float* wq = (const float*)d_in[4];
  const float* wk = (const float*)d_in[5];
  const float* wv = (const float*)d_in[6];
  float* out = (float*)d_out;

  char* ws = (char*)d_ws;
  f16* Qws = (f16*)(ws);              //  8.39 MB
  f16* Kws = (f16*)(ws + 8388608);    //  8.39 MB
  f16* Vtws = (f16*)(ws + 16777216);  //  8.39 MB
  f16* wT = (f16*)(ws + 25165824);    //  1.57 MB (total ~26.7 MB)

  prep_w<<<dim3(8, 8, 3), 256, 0, stream>>>(wq, wk, wv, wT);
  qkv_gemm<<<dim3(256, 1, 3), 256, 0, stream>>>(query, key, value, wT, Qws,
                                                Kws, Vtws);
  flash_attn<<<dim3(32, 16), 256, 0, stream>>>(Qws, Kws, Vtws, key_mask, out);
}